// Round 4
// baseline (406.220 us; speedup 1.0000x reference)
//
#include <hip/hip_runtime.h>

// Problem constants: B=8, N=7, C=64, H=128, W=128
#define NB     8
#define NN     7
#define D_EL   (64*128*128)       // 1048576 floats per (b,n)
#define DV2    (D_EL/2)           // 524288 float2 per (b,n)
#define NPAIR  28                 // unique (i<=j) pairs of 7
#define BPB    256                // blocks per batch (gram partials)
#define BPB3   512                // blocks per batch (apply)
#define THREADS 256

typedef float f32x2 __attribute__((ext_vector_type(2)));

__device__ __forceinline__ int pair_idx(int i, int j) {
    return i * 7 - (i * (i - 1)) / 2 + (j - i);
}

// ---------------------------------------------------------------------------
// Kernel 1: per-block partial Gram sums.  grid = NB*BPB blocks.
// float2 loads keep VGPR < 64 -> 8 waves/SIMD.
// ---------------------------------------------------------------------------
__global__ __launch_bounds__(THREADS, 8)
void gram_partial(const float* __restrict__ x2, float* __restrict__ partials) {
    const int b   = blockIdx.x / BPB;
    const int blk = blockIdx.x % BPB;
    const f32x2* base = (const f32x2*)(x2 + (size_t)b * NN * D_EL);

    float acc[NPAIR];
#pragma unroll
    for (int k = 0; k < NPAIR; ++k) acc[k] = 0.f;

    for (int p = blk * THREADS + threadIdx.x; p < DV2; p += BPB * THREADS) {
        f32x2 v[NN];
#pragma unroll
        for (int n = 0; n < NN; ++n) v[n] = base[(size_t)n * DV2 + p];
        int k = 0;
#pragma unroll
        for (int i = 0; i < NN; ++i)
#pragma unroll
            for (int j = i; j < NN; ++j, ++k) {
                acc[k] = fmaf(v[i].x, v[j].x, acc[k]);
                acc[k] = fmaf(v[i].y, v[j].y, acc[k]);
            }
    }

    __shared__ float lds[4][NPAIR];
    const int lane = threadIdx.x & 63;
    const int wid  = threadIdx.x >> 6;
#pragma unroll
    for (int k = 0; k < NPAIR; ++k) {
        float s = acc[k];
#pragma unroll
        for (int o = 32; o > 0; o >>= 1) s += __shfl_down(s, o, 64);
        if (lane == 0) lds[wid][k] = s;
    }
    __syncthreads();
    if (threadIdx.x < NPAIR) {
        float s = lds[0][threadIdx.x] + lds[1][threadIdx.x]
                + lds[2][threadIdx.x] + lds[3][threadIdx.x];
        partials[(size_t)blockIdx.x * NPAIR + threadIdx.x] = s;
    }
}

// ---------------------------------------------------------------------------
// Kernel 2: reduce partials -> energy (7x7) -> attention.
// softmax(rowmax(E)-E) == softmax(-E) (shift-invariant).
// ---------------------------------------------------------------------------
__global__ __launch_bounds__(THREADS)
void softmax_k(const float* __restrict__ partials, float* __restrict__ att) {
    const int b = blockIdx.x;
    const float* pb = partials + (size_t)b * BPB * NPAIR;

    float acc[NPAIR];
#pragma unroll
    for (int k = 0; k < NPAIR; ++k) acc[k] = pb[(size_t)threadIdx.x * NPAIR + k];

    __shared__ float lds[4][NPAIR];
    __shared__ float e_s[NPAIR];
    const int lane = threadIdx.x & 63;
    const int wid  = threadIdx.x >> 6;
#pragma unroll
    for (int k = 0; k < NPAIR; ++k) {
        float s = acc[k];
#pragma unroll
        for (int o = 32; o > 0; o >>= 1) s += __shfl_down(s, o, 64);
        if (lane == 0) lds[wid][k] = s;
    }
    __syncthreads();
    if (threadIdx.x < NPAIR) {
        e_s[threadIdx.x] = lds[0][threadIdx.x] + lds[1][threadIdx.x]
                         + lds[2][threadIdx.x] + lds[3][threadIdx.x];
    }
    __syncthreads();

    if (threadIdx.x < NN) {
        const int n = threadIdx.x;
        float z[NN];
#pragma unroll
        for (int m = 0; m < NN; ++m) {
            const int i = n < m ? n : m;
            const int j = n < m ? m : n;
            z[m] = -e_s[pair_idx(i, j)];
        }
        float mx = z[0];
#pragma unroll
        for (int m = 1; m < NN; ++m) mx = fmaxf(mx, z[m]);
        float p[NN], s = 0.f;
#pragma unroll
        for (int m = 0; m < NN; ++m) { p[m] = expf(z[m] - mx); s += p[m]; }
        const float inv = 1.f / s;
#pragma unroll
        for (int m = 0; m < NN; ++m)
            att[(size_t)b * NN * NN + n * NN + m] = p[m] * inv;
    }
}

// ---------------------------------------------------------------------------
// Kernel 3: out[b,n,d] = x1 * (1 + gamma * sum_m att[n,m] * x2[b,m,d])
// float2, plain loads/stores (nontemporal hints REGRESSED: 2x WRITE_SIZE,
// L3 x2 residency lost -> 3x FETCH).  x2 expected L3-hot from gram pass.
// ---------------------------------------------------------------------------
__global__ __launch_bounds__(THREADS, 8)
void apply_k(const float* __restrict__ x1, const float* __restrict__ x2,
             const float* __restrict__ att, const float* __restrict__ gamma,
             float* __restrict__ out) {
    const int b   = blockIdx.x / BPB3;
    const int blk = blockIdx.x % BPB3;

    __shared__ float a_s[NN * NN];
    if (threadIdx.x < NN * NN)
        a_s[threadIdx.x] = att[(size_t)b * NN * NN + threadIdx.x];
    __syncthreads();

    const float g = gamma[0];
    const f32x2* v2 = (const f32x2*)(x2 + (size_t)b * NN * D_EL);
    const f32x2* v1 = (const f32x2*)(x1 + (size_t)b * NN * D_EL);
    f32x2*       vo = (f32x2*)((float*)out + (size_t)b * NN * D_EL);

    for (int p = blk * THREADS + threadIdx.x; p < DV2; p += BPB3 * THREADS) {
        f32x2 v[NN];
        f32x2 x[NN];
#pragma unroll
        for (int m = 0; m < NN; ++m) v[m] = v2[(size_t)m * DV2 + p];
#pragma unroll
        for (int n = 0; n < NN; ++n) x[n] = v1[(size_t)n * DV2 + p];
#pragma unroll
        for (int n = 0; n < NN; ++n) {
            float ox = 0.f, oy = 0.f;
#pragma unroll
            for (int m = 0; m < NN; ++m) {
                const float a = a_s[n * NN + m];
                ox = fmaf(a, v[m].x, ox);
                oy = fmaf(a, v[m].y, oy);
            }
            f32x2 r;
            r.x = fmaf(x[n].x, g * ox, x[n].x);
            r.y = fmaf(x[n].y, g * oy, x[n].y);
            vo[(size_t)n * DV2 + p] = r;
        }
    }
}

extern "C" void kernel_launch(void* const* d_in, const int* in_sizes, int n_in,
                              void* d_out, int out_size, void* d_ws, size_t ws_size,
                              hipStream_t stream) {
    const float* x1    = (const float*)d_in[0];
    const float* x2    = (const float*)d_in[1];
    const float* gamma = (const float*)d_in[2];
    float*       out   = (float*)d_out;

    float* partials = (float*)d_ws;                         // NB*BPB*NPAIR floats
    float* att      = partials + (size_t)NB * BPB * NPAIR;  // NB*49 floats

    gram_partial<<<dim3(NB * BPB),  dim3(THREADS), 0, stream>>>(x2, partials);
    softmax_k  <<<dim3(NB),         dim3(THREADS), 0, stream>>>(partials, att);
    apply_k    <<<dim3(NB * BPB3),  dim3(THREADS), 0, stream>>>(x1, x2, att, gamma, out);
}

// Round 5
// 240.249 us; speedup vs baseline: 1.6908x; 1.6908x over previous
//
#include <hip/hip_runtime.h>

// Problem constants: B=8, N=7, C=64, H=128, W=128
#define NB     8
#define NN     7
#define D_EL   (64*128*128)       // 1048576 floats per (b,n)
#define DV     (D_EL/4)           // 262144 float4 per (b,n)
#define NPAIR  28                 // unique (i<=j) pairs of 7
#define BPB    256                // blocks per batch (gram partials)
#define THREADS 256

// apply_k chunking: each block = one (batch, chunk, n); 16KB contiguous
// per HBM stream (x1 read, out write); x2 via same-XCD L2 sharing.
#define CHUNK  1024               // float4 per chunk (16KB)
#define CPB    (DV/CHUNK)         // 256 chunks per batch
#define NXCD   8
#define GPX    ((NB*CPB)/NXCD)    // 256 groups per XCD
#define SLOTS  (GPX*NN)           // 1792 slots per XCD

__device__ __forceinline__ int pair_idx(int i, int j) {
    return i * 7 - (i * (i - 1)) / 2 + (j - i);
}

// ---------------------------------------------------------------------------
// Kernel 1: per-block partial Gram sums (R1-exact float4 version).
// ---------------------------------------------------------------------------
__global__ __launch_bounds__(THREADS)
void gram_partial(const float* __restrict__ x2, float* __restrict__ partials) {
    const int b   = blockIdx.x / BPB;
    const int blk = blockIdx.x % BPB;
    const float4* base = (const float4*)(x2 + (size_t)b * NN * D_EL);

    float acc[NPAIR];
#pragma unroll
    for (int k = 0; k < NPAIR; ++k) acc[k] = 0.f;

    for (int p = blk * THREADS + threadIdx.x; p < DV; p += BPB * THREADS) {
        float4 v[NN];
#pragma unroll
        for (int n = 0; n < NN; ++n) v[n] = base[(size_t)n * DV + p];
        int k = 0;
#pragma unroll
        for (int i = 0; i < NN; ++i)
#pragma unroll
            for (int j = i; j < NN; ++j, ++k) {
                acc[k] = fmaf(v[i].x, v[j].x, acc[k]);
                acc[k] = fmaf(v[i].y, v[j].y, acc[k]);
                acc[k] = fmaf(v[i].z, v[j].z, acc[k]);
                acc[k] = fmaf(v[i].w, v[j].w, acc[k]);
            }
    }

    __shared__ float lds[4][NPAIR];
    const int lane = threadIdx.x & 63;
    const int wid  = threadIdx.x >> 6;
#pragma unroll
    for (int k = 0; k < NPAIR; ++k) {
        float s = acc[k];
#pragma unroll
        for (int o = 32; o > 0; o >>= 1) s += __shfl_down(s, o, 64);
        if (lane == 0) lds[wid][k] = s;
    }
    __syncthreads();
    if (threadIdx.x < NPAIR) {
        float s = lds[0][threadIdx.x] + lds[1][threadIdx.x]
                + lds[2][threadIdx.x] + lds[3][threadIdx.x];
        partials[(size_t)blockIdx.x * NPAIR + threadIdx.x] = s;
    }
}

// ---------------------------------------------------------------------------
// Kernel 2: reduce partials -> energy (7x7) -> attention.
// softmax(rowmax(E)-E) == softmax(-E) (shift-invariant).
// ---------------------------------------------------------------------------
__global__ __launch_bounds__(THREADS)
void softmax_k(const float* __restrict__ partials, float* __restrict__ att) {
    const int b = blockIdx.x;
    const float* pb = partials + (size_t)b * BPB * NPAIR;

    float acc[NPAIR];
#pragma unroll
    for (int k = 0; k < NPAIR; ++k) acc[k] = pb[(size_t)threadIdx.x * NPAIR + k];

    __shared__ float lds[4][NPAIR];
    __shared__ float e_s[NPAIR];
    const int lane = threadIdx.x & 63;
    const int wid  = threadIdx.x >> 6;
#pragma unroll
    for (int k = 0; k < NPAIR; ++k) {
        float s = acc[k];
#pragma unroll
        for (int o = 32; o > 0; o >>= 1) s += __shfl_down(s, o, 64);
        if (lane == 0) lds[wid][k] = s;
    }
    __syncthreads();
    if (threadIdx.x < NPAIR) {
        e_s[threadIdx.x] = lds[0][threadIdx.x] + lds[1][threadIdx.x]
                         + lds[2][threadIdx.x] + lds[3][threadIdx.x];
    }
    __syncthreads();

    if (threadIdx.x < NN) {
        const int n = threadIdx.x;
        float z[NN];
#pragma unroll
        for (int m = 0; m < NN; ++m) {
            const int i = n < m ? n : m;
            const int j = n < m ? m : n;
            z[m] = -e_s[pair_idx(i, j)];
        }
        float mx = z[0];
#pragma unroll
        for (int m = 1; m < NN; ++m) mx = fmaxf(mx, z[m]);
        float p[NN], s = 0.f;
#pragma unroll
        for (int m = 0; m < NN; ++m) { p[m] = expf(z[m] - mx); s += p[m]; }
        const float inv = 1.f / s;
#pragma unroll
        for (int m = 0; m < NN; ++m)
            att[(size_t)b * NN * NN + n * NN + m] = p[m] * inv;
    }
}

// ---------------------------------------------------------------------------
// Kernel 3: out[b,n,p] = x1[b,n,p] * (1 + g * sum_m att[n,m] * x2[b,m,p])
// One block per (b, chunk, n): 1 contiguous x1 read stream + 1 contiguous
// out write stream (copy-like HBM pattern, float4 full-line stores).
// The 7 n-blocks of a (b,chunk) group sit at consecutive slots on the SAME
// XCD (bid%8 = XCD round-robin), so x2 chunk reads hit that XCD's L2 6/7
// of the time; the remaining 1/7 hits L3 (warmed by gram_partial).
// ---------------------------------------------------------------------------
__global__ __launch_bounds__(THREADS)
void apply_k(const float* __restrict__ x1, const float* __restrict__ x2,
             const float* __restrict__ att, const float* __restrict__ gamma,
             float* __restrict__ out) {
    const int bid   = blockIdx.x;
    const int xcd   = bid & (NXCD - 1);
    const int slot  = bid >> 3;          // [0, SLOTS)
    const int g     = xcd * GPX + slot / NN;
    const int n     = slot % NN;
    const int b     = g / CPB;
    const int chunk = g % CPB;

    const float gm = gamma[0];
    const float* arow = att + (size_t)b * NN * NN + n * NN;
    float a[NN];
#pragma unroll
    for (int m = 0; m < NN; ++m) a[m] = arow[m];

    const float4* v2 = (const float4*)(x2 + (size_t)b * NN * D_EL);
    const float4* v1 = (const float4*)(x1 + (size_t)b * NN * D_EL) + (size_t)n * DV;
    float4*       vo = (float4*)((float*)out + (size_t)b * NN * D_EL) + (size_t)n * DV;

    const int p0 = chunk * CHUNK;
#pragma unroll
    for (int it = 0; it < CHUNK / THREADS; ++it) {
        const int p = p0 + it * THREADS + threadIdx.x;
        const float4 xv = v1[p];
        float ox = 0.f, oy = 0.f, oz = 0.f, ow = 0.f;
#pragma unroll
        for (int m = 0; m < NN; ++m) {
            const float4 v = v2[(size_t)m * DV + p];
            ox = fmaf(a[m], v.x, ox);
            oy = fmaf(a[m], v.y, oy);
            oz = fmaf(a[m], v.z, oz);
            ow = fmaf(a[m], v.w, ow);
        }
        float4 r;
        r.x = fmaf(xv.x, gm * ox, xv.x);
        r.y = fmaf(xv.y, gm * oy, xv.y);
        r.z = fmaf(xv.z, gm * oz, xv.z);
        r.w = fmaf(xv.w, gm * ow, xv.w);
        vo[p] = r;
    }
}

extern "C" void kernel_launch(void* const* d_in, const int* in_sizes, int n_in,
                              void* d_out, int out_size, void* d_ws, size_t ws_size,
                              hipStream_t stream) {
    const float* x1    = (const float*)d_in[0];
    const float* x2    = (const float*)d_in[1];
    const float* gamma = (const float*)d_in[2];
    float*       out   = (float*)d_out;

    float* partials = (float*)d_ws;                         // NB*BPB*NPAIR floats
    float* att      = partials + (size_t)NB * BPB * NPAIR;  // NB*49 floats

    gram_partial<<<dim3(NB * BPB),      dim3(THREADS), 0, stream>>>(x2, partials);
    softmax_k  <<<dim3(NB),             dim3(THREADS), 0, stream>>>(partials, att);
    apply_k    <<<dim3(NXCD * SLOTS),   dim3(THREADS), 0, stream>>>(x1, x2, att, gamma, out);
}

// Round 6
// 209.211 us; speedup vs baseline: 1.9417x; 1.1484x over previous
//
#include <hip/hip_runtime.h>

// Problem constants: B=8, N=7, C=64, H=128, W=128
#define NB     8
#define NN     7
#define D_EL   (64*128*128)       // 1048576 floats per (b,n)
#define DV     (D_EL/4)           // 262144 float4 per (b,n)
#define NPAIR  28                 // unique (i<=j) pairs of 7
#define BPB    256                // blocks per batch (gram + apply)
#define CHUNKV (DV/BPB)           // 1024 float4 per block per stream (16KB)
#define ITERS  (CHUNKV/256)       // 4 contiguous 4KB steps
#define THREADS 256

__device__ __forceinline__ int pair_idx(int i, int j) {
    return i * 7 - (i * (i - 1)) / 2 + (j - i);
}

// ---------------------------------------------------------------------------
// Kernel 1: per-block partial Gram sums.  Each block owns a CONTIGUOUS
// 16KB chunk per stream (vs grid-stride 1MB hops) for DRAM page locality.
// ---------------------------------------------------------------------------
__global__ __launch_bounds__(THREADS)
void gram_partial(const float* __restrict__ x2, float* __restrict__ partials) {
    const int b   = blockIdx.x / BPB;
    const int blk = blockIdx.x % BPB;
    const float4* base = (const float4*)(x2 + (size_t)b * NN * D_EL);
    const int p0 = blk * CHUNKV;

    float acc[NPAIR];
#pragma unroll
    for (int k = 0; k < NPAIR; ++k) acc[k] = 0.f;

#pragma unroll
    for (int it = 0; it < ITERS; ++it) {
        const int p = p0 + it * THREADS + threadIdx.x;
        float4 v[NN];
#pragma unroll
        for (int n = 0; n < NN; ++n) v[n] = base[(size_t)n * DV + p];
        int k = 0;
#pragma unroll
        for (int i = 0; i < NN; ++i)
#pragma unroll
            for (int j = i; j < NN; ++j, ++k) {
                acc[k] = fmaf(v[i].x, v[j].x, acc[k]);
                acc[k] = fmaf(v[i].y, v[j].y, acc[k]);
                acc[k] = fmaf(v[i].z, v[j].z, acc[k]);
                acc[k] = fmaf(v[i].w, v[j].w, acc[k]);
            }
    }

    __shared__ float lds[4][NPAIR];
    const int lane = threadIdx.x & 63;
    const int wid  = threadIdx.x >> 6;
#pragma unroll
    for (int k = 0; k < NPAIR; ++k) {
        float s = acc[k];
#pragma unroll
        for (int o = 32; o > 0; o >>= 1) s += __shfl_down(s, o, 64);
        if (lane == 0) lds[wid][k] = s;
    }
    __syncthreads();
    if (threadIdx.x < NPAIR) {
        float s = lds[0][threadIdx.x] + lds[1][threadIdx.x]
                + lds[2][threadIdx.x] + lds[3][threadIdx.x];
        partials[(size_t)blockIdx.x * NPAIR + threadIdx.x] = s;
    }
}

// ---------------------------------------------------------------------------
// Kernel 2: reduce partials -> energy (7x7) -> attention.
// softmax(rowmax(E)-E) == softmax(-E) (shift-invariant).
// ---------------------------------------------------------------------------
__global__ __launch_bounds__(THREADS)
void softmax_k(const float* __restrict__ partials, float* __restrict__ att) {
    const int b = blockIdx.x;
    const float* pb = partials + (size_t)b * BPB * NPAIR;

    float acc[NPAIR];
#pragma unroll
    for (int k = 0; k < NPAIR; ++k) acc[k] = pb[(size_t)threadIdx.x * NPAIR + k];

    __shared__ float lds[4][NPAIR];
    __shared__ float e_s[NPAIR];
    const int lane = threadIdx.x & 63;
    const int wid  = threadIdx.x >> 6;
#pragma unroll
    for (int k = 0; k < NPAIR; ++k) {
        float s = acc[k];
#pragma unroll
        for (int o = 32; o > 0; o >>= 1) s += __shfl_down(s, o, 64);
        if (lane == 0) lds[wid][k] = s;
    }
    __syncthreads();
    if (threadIdx.x < NPAIR) {
        e_s[threadIdx.x] = lds[0][threadIdx.x] + lds[1][threadIdx.x]
                         + lds[2][threadIdx.x] + lds[3][threadIdx.x];
    }
    __syncthreads();

    if (threadIdx.x < NN) {
        const int n = threadIdx.x;
        float z[NN];
#pragma unroll
        for (int m = 0; m < NN; ++m) {
            const int i = n < m ? n : m;
            const int j = n < m ? m : n;
            z[m] = -e_s[pair_idx(i, j)];
        }
        float mx = z[0];
#pragma unroll
        for (int m = 1; m < NN; ++m) mx = fmaxf(mx, z[m]);
        float p[NN], s = 0.f;
#pragma unroll
        for (int m = 0; m < NN; ++m) { p[m] = expf(z[m] - mx); s += p[m]; }
        const float inv = 1.f / s;
#pragma unroll
        for (int m = 0; m < NN; ++m)
            att[(size_t)b * NN * NN + n * NN + m] = p[m] * inv;
    }
}

// ---------------------------------------------------------------------------
// Kernel 3: out[b,n,p] = x1 * (1 + g * sum_m att[n,m] * x2[b,m,p])
// R1 register-reuse body (x2 read ONCE per position, used for all 7 n),
// but with contiguous per-block chunks: all 21 streams advance sequentially.
// x2 is L3-resident (gram warmed it; FETCH==x1 confirmed R1/R5).
// ---------------------------------------------------------------------------
__global__ __launch_bounds__(THREADS)
void apply_k(const float* __restrict__ x1, const float* __restrict__ x2,
             const float* __restrict__ att, const float* __restrict__ gamma,
             float* __restrict__ out) {
    const int b   = blockIdx.x / BPB;
    const int blk = blockIdx.x % BPB;

    __shared__ float a_s[NN * NN];
    if (threadIdx.x < NN * NN)
        a_s[threadIdx.x] = att[(size_t)b * NN * NN + threadIdx.x];
    __syncthreads();

    const float g = gamma[0];
    const float4* v2 = (const float4*)(x2 + (size_t)b * NN * D_EL);
    const float4* v1 = (const float4*)(x1 + (size_t)b * NN * D_EL);
    float4*       vo = (float4*)((float*)out + (size_t)b * NN * D_EL);
    const int p0 = blk * CHUNKV;

#pragma unroll
    for (int it = 0; it < ITERS; ++it) {
        const int p = p0 + it * THREADS + threadIdx.x;
        float4 v[NN];
#pragma unroll
        for (int m = 0; m < NN; ++m) v[m] = v2[(size_t)m * DV + p];
#pragma unroll
        for (int n = 0; n < NN; ++n) {
            float ox = 0.f, oy = 0.f, oz = 0.f, ow = 0.f;
#pragma unroll
            for (int m = 0; m < NN; ++m) {
                const float a = a_s[n * NN + m];
                ox = fmaf(a, v[m].x, ox);
                oy = fmaf(a, v[m].y, oy);
                oz = fmaf(a, v[m].z, oz);
                ow = fmaf(a, v[m].w, ow);
            }
            const float4 x = v1[(size_t)n * DV + p];
            float4 r;
            r.x = fmaf(x.x, g * ox, x.x);
            r.y = fmaf(x.y, g * oy, x.y);
            r.z = fmaf(x.z, g * oz, x.z);
            r.w = fmaf(x.w, g * ow, x.w);
            vo[(size_t)n * DV + p] = r;
        }
    }
}

extern "C" void kernel_launch(void* const* d_in, const int* in_sizes, int n_in,
                              void* d_out, int out_size, void* d_ws, size_t ws_size,
                              hipStream_t stream) {
    const float* x1    = (const float*)d_in[0];
    const float* x2    = (const float*)d_in[1];
    const float* gamma = (const float*)d_in[2];
    float*       out   = (float*)d_out;

    float* partials = (float*)d_ws;                         // NB*BPB*NPAIR floats
    float* att      = partials + (size_t)NB * BPB * NPAIR;  // NB*49 floats

    gram_partial<<<dim3(NB * BPB), dim3(THREADS), 0, stream>>>(x2, partials);
    softmax_k  <<<dim3(NB),        dim3(THREADS), 0, stream>>>(partials, att);
    apply_k    <<<dim3(NB * BPB),  dim3(THREADS), 0, stream>>>(x1, x2, att, gamma, out);
}

// Round 7
// 199.096 us; speedup vs baseline: 2.0403x; 1.0508x over previous
//
#include <hip/hip_runtime.h>

// Problem constants: B=8, N=7, C=64, H=128, W=128
#define NB     8
#define NN     7
#define D_EL   (64*128*128)       // 1048576 floats per (b,n)
#define DV     (D_EL/4)           // 262144 float4 per (b,n)
#define NPAIR  28                 // unique (i<=j) pairs of 7
#define BPB    256                // blocks per batch (gram)
#define CHUNKV (DV/BPB)           // 1024 float4 per gram block (16KB)
#define ITERS  (CHUNKV/256)
#define THREADS 256

// apply: one block per (b, chunk); chunk = 256 float4 per stream (4KB)
#define ACH    256                // float4 per apply chunk
#define ACPB   (DV/ACH)           // 1024 chunks per batch

__device__ __forceinline__ int pair_idx(int i, int j) {
    return i * 7 - (i * (i - 1)) / 2 + (j - i);
}

// ---------------------------------------------------------------------------
// Kernel 1: per-block partial Gram sums (R6 version, unchanged).
// ---------------------------------------------------------------------------
__global__ __launch_bounds__(THREADS)
void gram_partial(const float* __restrict__ x2, float* __restrict__ partials) {
    const int b   = blockIdx.x / BPB;
    const int blk = blockIdx.x % BPB;
    const float4* base = (const float4*)(x2 + (size_t)b * NN * D_EL);
    const int p0 = blk * CHUNKV;

    float acc[NPAIR];
#pragma unroll
    for (int k = 0; k < NPAIR; ++k) acc[k] = 0.f;

#pragma unroll
    for (int it = 0; it < ITERS; ++it) {
        const int p = p0 + it * THREADS + threadIdx.x;
        float4 v[NN];
#pragma unroll
        for (int n = 0; n < NN; ++n) v[n] = base[(size_t)n * DV + p];
        int k = 0;
#pragma unroll
        for (int i = 0; i < NN; ++i)
#pragma unroll
            for (int j = i; j < NN; ++j, ++k) {
                acc[k] = fmaf(v[i].x, v[j].x, acc[k]);
                acc[k] = fmaf(v[i].y, v[j].y, acc[k]);
                acc[k] = fmaf(v[i].z, v[j].z, acc[k]);
                acc[k] = fmaf(v[i].w, v[j].w, acc[k]);
            }
    }

    __shared__ float lds[4][NPAIR];
    const int lane = threadIdx.x & 63;
    const int wid  = threadIdx.x >> 6;
#pragma unroll
    for (int k = 0; k < NPAIR; ++k) {
        float s = acc[k];
#pragma unroll
        for (int o = 32; o > 0; o >>= 1) s += __shfl_down(s, o, 64);
        if (lane == 0) lds[wid][k] = s;
    }
    __syncthreads();
    if (threadIdx.x < NPAIR) {
        float s = lds[0][threadIdx.x] + lds[1][threadIdx.x]
                + lds[2][threadIdx.x] + lds[3][threadIdx.x];
        partials[(size_t)blockIdx.x * NPAIR + threadIdx.x] = s;
    }
}

// ---------------------------------------------------------------------------
// Kernel 2: reduce partials -> energy (7x7) -> attention.
// softmax(rowmax(E)-E) == softmax(-E) (shift-invariant).
// ---------------------------------------------------------------------------
__global__ __launch_bounds__(THREADS)
void softmax_k(const float* __restrict__ partials, float* __restrict__ att) {
    const int b = blockIdx.x;
    const float* pb = partials + (size_t)b * BPB * NPAIR;

    float acc[NPAIR];
#pragma unroll
    for (int k = 0; k < NPAIR; ++k) acc[k] = pb[(size_t)threadIdx.x * NPAIR + k];

    __shared__ float lds[4][NPAIR];
    __shared__ float e_s[NPAIR];
    const int lane = threadIdx.x & 63;
    const int wid  = threadIdx.x >> 6;
#pragma unroll
    for (int k = 0; k < NPAIR; ++k) {
        float s = acc[k];
#pragma unroll
        for (int o = 32; o > 0; o >>= 1) s += __shfl_down(s, o, 64);
        if (lane == 0) lds[wid][k] = s;
    }
    __syncthreads();
    if (threadIdx.x < NPAIR) {
        e_s[threadIdx.x] = lds[0][threadIdx.x] + lds[1][threadIdx.x]
                         + lds[2][threadIdx.x] + lds[3][threadIdx.x];
    }
    __syncthreads();

    if (threadIdx.x < NN) {
        const int n = threadIdx.x;
        float z[NN];
#pragma unroll
        for (int m = 0; m < NN; ++m) {
            const int i = n < m ? n : m;
            const int j = n < m ? m : n;
            z[m] = -e_s[pair_idx(i, j)];
        }
        float mx = z[0];
#pragma unroll
        for (int m = 1; m < NN; ++m) mx = fmaxf(mx, z[m]);
        float p[NN], s = 0.f;
#pragma unroll
        for (int m = 0; m < NN; ++m) { p[m] = expf(z[m] - mx); s += p[m]; }
        const float inv = 1.f / s;
#pragma unroll
        for (int m = 0; m < NN; ++m)
            att[(size_t)b * NN * NN + n * NN + m] = p[m] * inv;
    }
}

// ---------------------------------------------------------------------------
// Kernel 3: phase-separated LDS-staged apply.
//   Phase 1: burst-load the 7 x2 sub-streams (4KB each, L3-served) into LDS.
//   Phase 2: each thread pulls its 7 x2 float4 from LDS into regs once, then
//            runs 7 clean copy-like (x1 read -> out write) stream pairs.
// Avoids the 21-way fine-grained stream interleave of R1/R6.
// ---------------------------------------------------------------------------
__global__ __launch_bounds__(THREADS)
void apply_k(const float* __restrict__ x1, const float* __restrict__ x2,
             const float* __restrict__ att, const float* __restrict__ gamma,
             float* __restrict__ out) {
    const int b     = blockIdx.x / ACPB;
    const int chunk = blockIdx.x % ACPB;
    const int p0    = chunk * ACH;

    __shared__ float4 x2s[NN * ACH];     // 28 KB
    __shared__ float  a_s[NN * NN];

    if (threadIdx.x < NN * NN)
        a_s[threadIdx.x] = att[(size_t)b * NN * NN + threadIdx.x];

    const float4* v2 = (const float4*)(x2 + (size_t)b * NN * D_EL);
    // Phase 1: 7 loads per thread, each m a contiguous 4KB burst.
#pragma unroll
    for (int m = 0; m < NN; ++m)
        x2s[m * ACH + threadIdx.x] = v2[(size_t)m * DV + p0 + threadIdx.x];
    __syncthreads();

    // Pull this thread's column of x2 into registers (one LDS pass).
    float4 v[NN];
#pragma unroll
    for (int m = 0; m < NN; ++m) v[m] = x2s[m * ACH + threadIdx.x];

    const float g = gamma[0];
    const float4* v1 = (const float4*)(x1 + (size_t)b * NN * D_EL);
    float4*       vo = (float4*)((float*)out + (size_t)b * NN * D_EL);
    const int p = p0 + threadIdx.x;

    // Phase 2: seven copy-like read->write stream pairs.
#pragma unroll
    for (int n = 0; n < NN; ++n) {
        const float4 x = v1[(size_t)n * DV + p];
        float ox = 0.f, oy = 0.f, oz = 0.f, ow = 0.f;
#pragma unroll
        for (int m = 0; m < NN; ++m) {
            const float a = a_s[n * NN + m];
            ox = fmaf(a, v[m].x, ox);
            oy = fmaf(a, v[m].y, oy);
            oz = fmaf(a, v[m].z, oz);
            ow = fmaf(a, v[m].w, ow);
        }
        float4 r;
        r.x = fmaf(x.x, g * ox, x.x);
        r.y = fmaf(x.y, g * oy, x.y);
        r.z = fmaf(x.z, g * oz, x.z);
        r.w = fmaf(x.w, g * ow, x.w);
        vo[(size_t)n * DV + p] = r;
    }
}

extern "C" void kernel_launch(void* const* d_in, const int* in_sizes, int n_in,
                              void* d_out, int out_size, void* d_ws, size_t ws_size,
                              hipStream_t stream) {
    const float* x1    = (const float*)d_in[0];
    const float* x2    = (const float*)d_in[1];
    const float* gamma = (const float*)d_in[2];
    float*       out   = (float*)d_out;

    float* partials = (float*)d_ws;                         // NB*BPB*NPAIR floats
    float* att      = partials + (size_t)NB * BPB * NPAIR;  // NB*49 floats

    gram_partial<<<dim3(NB * BPB),  dim3(THREADS), 0, stream>>>(x2, partials);
    softmax_k  <<<dim3(NB),         dim3(THREADS), 0, stream>>>(partials, att);
    apply_k    <<<dim3(NB * ACPB),  dim3(THREADS), 0, stream>>>(x1, x2, att, gamma, out);
}